// Round 10
// baseline (10414.471 us; speedup 1.0000x reference)
//
#include <hip/hip_runtime.h>

typedef unsigned short u16;
typedef __attribute__((ext_vector_type(8))) short short8;
typedef __attribute__((ext_vector_type(4))) float f32x4;

#define DEV __device__ __forceinline__

// B=192, T=64, ACT=16, EMB=1024, STOCH=32, DETER=600, HID=600
// out row stride 1392: [mean_po 0, std_po 32, stoch_po 64, deter 96,
//                       mean_pr 696, std_pr 728, stoch_pr 760, deter 792]

DEV u16 f2bf(float f) {
  unsigned u = __float_as_uint(f);
  u = (u + 0x7FFFu + ((u >> 16) & 1u)) >> 16;
  return (u16)u;
}
DEV float bf2f(u16 h) { return __uint_as_float(((unsigned)h) << 16); }
DEV float sigf(float x) { return 1.f / (1.f + __expf(-x)); }
DEV float eluf(float x) { return x > 0.f ? x : __expf(x) - 1.f; }
DEV f32x4 MF(short8 a, short8 b, f32x4 c) {
  return __builtin_amdgcn_mfma_f32_16x16x32_bf16(a, b, c, 0, 0, 0);
}

// ---------------- f32 -> bf16 with zero row padding (k-major) ----------------
__global__ __launch_bounds__(256) void conv_pad(const float* __restrict__ src,
                                                u16* __restrict__ dst,
                                                int K, int N, int Kpad, int srcRowOff) {
  size_t total = (size_t)Kpad * N;
  for (size_t idx = (size_t)blockIdx.x * 256 + threadIdx.x; idx < total;
       idx += (size_t)gridDim.x * 256) {
    int k = (int)(idx / (size_t)N);
    int n = (int)(idx % (size_t)N);
    dst[idx] = (k < K) ? f2bf(src[(size_t)(k + srcRowOff) * N + n]) : (u16)0;
  }
}

// ---------------- f32 [K0][N0] -> bf16 transposed [Npad][Kpad] ----------------
__global__ __launch_bounds__(256) void conv_T(const float* __restrict__ src,
                                              u16* __restrict__ dst,
                                              int K0, int N0, int Kpad, int Npad) {
  size_t total = (size_t)Npad * Kpad;
  for (size_t idx = (size_t)blockIdx.x * 256 + threadIdx.x; idx < total;
       idx += (size_t)gridDim.x * 256) {
    int n = (int)(idx / (size_t)Kpad);
    int k = (int)(idx % (size_t)Kpad);
    dst[idx] = (k < K0 && n < N0) ? f2bf(src[(size_t)k * N0 + n]) : (u16)0;
  }
}

// ---- gruw [1200][1800] -> bf16 [1808][1216], K remapped to scan's al layout:
// ---- k2 0..599 = x rows 0..599 ; 600..607 = 0 ; 608..1207 = deter rows
// ---- 600..1199 ; 1208..1215 = 0. Rows n >= 1800 zero.
__global__ __launch_bounds__(256) void conv_gruT(const float* __restrict__ src,
                                                 u16* __restrict__ dst) {
  size_t total = 1808ull * 1216;
  for (size_t idx = (size_t)blockIdx.x * 256 + threadIdx.x; idx < total;
       idx += (size_t)gridDim.x * 256) {
    int n = (int)(idx / 1216);
    int k2 = (int)(idx % 1216);
    int ko = (k2 < 600) ? k2 : (k2 >= 608 && k2 < 1208) ? (k2 - 8) : -1;
    dst[idx] = (n < 1800 && ko >= 0) ? f2bf(src[(size_t)ko * 1800 + n]) : (u16)0;
  }
}

// ---------------- MFMA 64x64 tile core (LDS-staged, for setup/tail GEMMs) ----
DEV void mfma_tile(const u16 (*As)[72], const u16 (*Bs)[72], int wm, int wn,
                   int lane, f32x4 acc[2][2]) {
#pragma unroll
  for (int s = 0; s < 2; ++s) {
    const int ko = s * 32 + ((lane >> 4) << 3);
    short8 a0 = *reinterpret_cast<const short8*>(&As[wm + (lane & 15)][ko]);
    short8 a1 = *reinterpret_cast<const short8*>(&As[wm + 16 + (lane & 15)][ko]);
    short8 b0 = *reinterpret_cast<const short8*>(&Bs[wn + (lane & 15)][ko]);
    short8 b1 = *reinterpret_cast<const short8*>(&Bs[wn + 16 + (lane & 15)][ko]);
    acc[0][0] = MF(a0, b0, acc[0][0]);
    acc[0][1] = MF(a0, b1, acc[0][1]);
    acc[1][0] = MF(a1, b0, acc[1][0]);
    acc[1][1] = MF(a1, b1, acc[1][1]);
  }
}

// ---------------- generic 64x64-tiled bf16 GEMM (setup/tail) ----------------
// EPI: 2 = +bias, elu, bf16 out ; 4 = +bias, bf16 out, epre-permuted store
template <int EPI>
__global__ __launch_bounds__(256) void gemm64(
    const u16* __restrict__ A, int lda, const u16* __restrict__ W, int ldw,
    const float* __restrict__ bias, void* __restrict__ Cv, int ldc,
    int Nstore, int N, int K) {
  __shared__ u16 As[64][72];
  __shared__ u16 Bs[64][72];
  const int tid = threadIdx.x, lane = tid & 63, wave = tid >> 6;
  const int wm = (wave & 1) * 32, wn = (wave >> 1) * 32;
  const int bn0 = blockIdx.x * 64, bm0 = blockIdx.y * 64;
  const int am = tid >> 2, ak0 = (tid & 3) * 16;
  const int bk = tid >> 3, bn = (tid & 7) * 8;

  f32x4 acc[2][2] = {};
  for (int k0 = 0; k0 < K; k0 += 64) {
    __syncthreads();
    {
      const u16* src = A + (size_t)(bm0 + am) * lda + k0 + ak0;
      *reinterpret_cast<short8*>(&As[am][ak0]) = *reinterpret_cast<const short8*>(src);
      *reinterpret_cast<short8*>(&As[am][ak0 + 8]) = *reinterpret_cast<const short8*>(src + 8);
    }
    {
      int gn = bn0 + bn;
#pragma unroll
      for (int h = 0; h < 2; ++h) {
        int kk = k0 + bk + h * 32;
        short8 v;
        if (gn + 7 < N) {
          v = *reinterpret_cast<const short8*>(W + (size_t)kk * ldw + gn);
        } else {
          for (int j = 0; j < 8; ++j)
            v[j] = (gn + j < N) ? (short)W[(size_t)kk * ldw + gn + j] : (short)0;
        }
#pragma unroll
        for (int j = 0; j < 8; ++j) Bs[bn + j][bk + h * 32] = (u16)v[j];
      }
    }
    __syncthreads();
    mfma_tile(As, Bs, wm, wn, lane, acc);
  }

#pragma unroll
  for (int r = 0; r < 2; ++r)
#pragma unroll
    for (int c = 0; c < 2; ++c)
#pragma unroll
      for (int i = 0; i < 4; ++i) {
        int grow = bm0 + wm + r * 16 + ((lane >> 4) << 2) + i;
        int gcol = bn0 + wn + c * 16 + (lane & 15);
        if (gcol >= Nstore) continue;
        bool ok = gcol < N;
        float v = acc[r][c][i] + (ok ? bias[gcol] : 0.f);
        if (EPI == 2) {
          v = eluf(v);
          ((u16*)Cv)[(size_t)grow * ldc + gcol] = ok ? f2bf(v) : (u16)0;
        } else {  // EPI 4: epre[t][b][600] layout
          size_t row2 = (size_t)(grow & 63) * 192 + (size_t)(grow >> 6);
          ((u16*)Cv)[row2 * 600 + gcol] = f2bf(v);
        }
      }
}

// ---------------- batched prior head (tail; N=64 GEMM + dist outputs) --------
__global__ __launch_bounds__(256) void head_prior(
    const u16* __restrict__ A, const u16* __restrict__ W,
    const float* __restrict__ bias64, const float* __restrict__ noise,
    float* __restrict__ out) {
  __shared__ u16 As[64][72];
  __shared__ u16 Bs[64][72];
  __shared__ float sl[64][68];
  const int tid = threadIdx.x, lane = tid & 63, wave = tid >> 6;
  const int wm = (wave & 1) * 32, wn = (wave >> 1) * 32;
  const int bm0 = blockIdx.x * 64;
  const int am = tid >> 2, ak0 = (tid & 3) * 16;
  const int bk = tid >> 3, bn = (tid & 7) * 8;

  f32x4 acc[2][2] = {};
  for (int k0 = 0; k0 < 640; k0 += 64) {
    __syncthreads();
    {
      const u16* src = A + (size_t)(bm0 + am) * 640 + k0 + ak0;
      *reinterpret_cast<short8*>(&As[am][ak0]) = *reinterpret_cast<const short8*>(src);
      *reinterpret_cast<short8*>(&As[am][ak0 + 8]) = *reinterpret_cast<const short8*>(src + 8);
    }
#pragma unroll
    for (int h = 0; h < 2; ++h) {
      int kk = k0 + bk + h * 32;
      short8 v = *reinterpret_cast<const short8*>(W + (size_t)kk * 64 + bn);
#pragma unroll
      for (int j = 0; j < 8; ++j) Bs[bn + j][bk + h * 32] = (u16)v[j];
    }
    __syncthreads();
    mfma_tile(As, Bs, wm, wn, lane, acc);
  }
#pragma unroll
  for (int r = 0; r < 2; ++r)
#pragma unroll
    for (int c = 0; c < 2; ++c)
#pragma unroll
      for (int i = 0; i < 4; ++i) {
        int col = wn + c * 16 + (lane & 15);
        sl[wm + r * 16 + ((lane >> 4) << 2) + i][col] = acc[r][c][i] + bias64[col];
      }
  __syncthreads();
  for (int task = tid; task < 64 * 32; task += 256) {
    int r = task >> 5, j = task & 31;
    size_t orow = (size_t)(bm0 + r);
    size_t base = orow * 1392 + 696;
    float mean = sl[r][j];
    float sd = 2.f * sigf(0.5f * sl[r][32 + j]) + 0.1f;
    float st = mean + sd * noise[orow * 32 + j];
    out[base + j] = mean;
    out[base + 32 + j] = sd;
    out[base + 64 + j] = st;
  }
}

// ---- the scan: 12 FULLY INDEPENDENT blocks, 16 batch rows each. ------------
// All state (x, deter, parts, h) lives in LDS; the only global traffic is
// read-only weights (L2/IC resident) and NT-streamed inputs/outputs.
// No inter-block synchronization of any kind.
struct ScanArgs {
  const u16* gruwT;   // [1808][1216] K-remapped (x | pad | deter | pad)
  const float* grub;
  const float* lns;
  const float* lnb;
  u16* dall;          // [12288][640] (nt; read by tail)
  float* out;
  const u16* o1wT;    // [608][608]
  const u16* epre;    // [64][192][600] (t-major, nt loads)
  const u16* o2wT;    // [64][608]
  const float* obs2b;
  const float* npo;
  const u16* w1pT;    // [640][64]
  const float* img1b;
  const float* action;
};

__global__ __launch_bounds__(512, 1) void scan64(ScanArgs A) {
  const int tid = threadIdx.x;
  const int lane = tid & 63, wave = tid >> 6;
  const int l15 = lane & 15;
  const int koff = (lane >> 4) << 3;   // k-octet offset within 32-k slab
  const int crow = (lane >> 4) << 2;   // C-row base within 16
  const int R0 = blockIdx.x * 16;

  // al: [x 0..599 | 0-pad 600..607 | deter 608..1207 | 0-pad 1208..1215]
  __shared__ u16 al[16][1240];     // 39,680 B (stride 620 dw: 2-way b128, ok)
  __shared__ u16 pl[16][1800];     // 57,600 B parts+bias, bf16 (row-local reads)
  __shared__ float dsh[16][600];   // 38,400 B deter carry f32
  __shared__ u16 hl[16][616];      // 19,712 B obs1 output (608 used)
  __shared__ float sl[16][68];     //  4,352 B obs2 output
  __shared__ u16 xa[16][72];       //  2,304 B [stoch|action|pad] for img1

  auto img1 = [&]() {  // x = elu([stoch, action] @ img1_w + b) -> al[.][0..599]
    for (int g = wave; g < 38; g += 8) {
      const u16* bp = A.w1pT + (size_t)(g * 16 + l15) * 64 + koff;
      f32x4 ax{};
      ax = MF(*reinterpret_cast<const short8*>(&xa[l15][koff]),
              *reinterpret_cast<const short8*>(bp), ax);
      ax = MF(*reinterpret_cast<const short8*>(&xa[l15][32 + koff]),
              *reinterpret_cast<const short8*>(bp + 32), ax);
      int c = g * 16 + l15;
      if (c < 600) {
        float bi = A.img1b[c];
#pragma unroll
        for (int i = 0; i < 4; ++i)
          al[crow + i][c] = f2bf(eluf(ax[i] + bi));
      }
    }
  };

  // ---- init: al=0 (deter=0 + pads), dsh=0, x(0) from action(t=0) ----
  for (int i = tid; i < 16 * 1240; i += 512) ((u16*)al)[i] = 0;
  for (int i = tid; i < 16 * 600; i += 512) ((float*)dsh)[i] = 0.f;
  for (int i = tid; i < 16 * 72; i += 512) ((u16*)xa)[i] = 0;
  __syncthreads();
  if (tid < 256) {
    int r = tid >> 4, a = tid & 15;
    xa[r][32 + a] = f2bf(A.action[((size_t)(R0 + r) * 64) * 16 + a]);
  }
  __syncthreads();
  img1();
  __syncthreads();

  for (int t = 0; t < 64; ++t) {
    // ===== Phase 1: parts = [x|deter] @ gruw + b  (pl bf16) =====
    for (int j0 = 0; j0 < 15; j0 += 7) {
      if (wave + 8 * j0 >= 113) break;
      f32x4 acc[7] = {};
      const u16* bp[7];
      int cc[7];
#pragma unroll
      for (int jj = 0; jj < 7; ++jj) {
        int g = wave + 8 * (j0 + jj);
        bool v = g < 113;
        cc[jj] = v ? (16 * g + l15) : -1;
        bp[jj] = A.gruwT + (size_t)(v ? 16 * g + l15 : 0) * 1216 + koff;
      }
#pragma unroll 2
      for (int kk = 0; kk < 1216; kk += 32) {
        short8 a = *reinterpret_cast<const short8*>(&al[l15][koff + kk]);
#pragma unroll
        for (int jj = 0; jj < 7; ++jj)
          acc[jj] = MF(a, *reinterpret_cast<const short8*>(bp[jj] + kk), acc[jj]);
      }
#pragma unroll
      for (int jj = 0; jj < 7; ++jj) {
        int c = cc[jj];
        if (c >= 0 && c < 1800) {
          float gb = A.grub[c];
#pragma unroll
          for (int i = 0; i < 4; ++i) pl[crow + i][c] = f2bf(acc[jj][i] + gb);
        }
      }
    }
    __syncthreads();

    // ===== Phase 2: LN + gates + deter update (wave w: rows w, w+8) =====
    for (int rr = wave; rr < 16; rr += 8) {
      float s = 0.f;
      for (int j = lane; j < 1800; j += 64) s += bf2f(pl[rr][j]);
#pragma unroll
      for (int o = 32; o; o >>= 1) s += __shfl_xor(s, o);
      float m = s * (1.f / 1800.f);
      float q = 0.f;
      for (int j = lane; j < 1800; j += 64) {
        float d = bf2f(pl[rr][j]) - m;
        q += d * d;
      }
#pragma unroll
      for (int o = 32; o; o >>= 1) q += __shfl_xor(q, o);
      float rstd = rsqrtf(q * (1.f / 1800.f) + 1e-5f);
      for (int j = lane; j < 600; j += 64) {
        float p0 = (bf2f(pl[rr][j]) - m) * rstd * A.lns[j] + A.lnb[j];
        float p1 = (bf2f(pl[rr][600 + j]) - m) * rstd * A.lns[600 + j] + A.lnb[600 + j];
        float p2 = (bf2f(pl[rr][1200 + j]) - m) * rstd * A.lns[1200 + j] + A.lnb[1200 + j];
        float r = sigf(p0);
        float cd = tanhf(r * p1);
        float u = sigf(p2 - 1.f);
        float dn = u * cd + (1.f - u) * dsh[rr][j];
        dsh[rr][j] = dn;
        al[rr][608 + j] = f2bf(dn);
      }
    }
    __syncthreads();

    // ---- deter outputs (NT streams) ----
    for (int idx = tid; idx < 4800; idx += 512) {
      int r = idx / 300, jp = idx - r * 300, j = 2 * jp;
      float f0 = dsh[r][j], f1 = dsh[r][j + 1];
      unsigned pk = (unsigned)f2bf(f0) | ((unsigned)f2bf(f1) << 16);
      size_t orow = (size_t)(R0 + r) * 64 + t;
      __builtin_nontemporal_store(pk, (unsigned*)(A.dall + orow * 640 + j));
      float* ob = A.out + orow * 1392;
      __builtin_nontemporal_store(f0, ob + 96 + j);
      __builtin_nontemporal_store(f1, ob + 97 + j);
      __builtin_nontemporal_store(f0, ob + 792 + j);
      __builtin_nontemporal_store(f1, ob + 793 + j);
    }
    if (tid < 320) {
      int r = tid / 20, qd = tid - r * 20;
      size_t orow = (size_t)(R0 + r) * 64 + t;
      __builtin_nontemporal_store(0u, (unsigned*)(A.dall + orow * 640 + 600 + 2 * qd));
    }

    // ===== Phase 3: obs1  h = elu(deter @ obs1_w + epre) =====
    for (int g = wave; g < 38; g += 8) {
      const u16* bp = A.o1wT + (size_t)(g * 16 + l15) * 608 + koff;
      f32x4 acc{};
#pragma unroll 4
      for (int kk = 0; kk < 608; kk += 32)
        acc = MF(*reinterpret_cast<const short8*>(&al[l15][608 + koff + kk]),
                 *reinterpret_cast<const short8*>(bp + kk), acc);
      int c = g * 16 + l15;
#pragma unroll
      for (int i = 0; i < 4; ++i) {
        int r = crow + i;
        u16 h = 0;
        if (c < 600) {
          float ep = bf2f(__builtin_nontemporal_load(
              A.epre + ((size_t)t * 192 + R0 + r) * 600 + c));
          h = f2bf(eluf(acc[i] + ep));
        }
        hl[r][c] = h;
      }
    }
    __syncthreads();

    // ===== Phase 4: obs2 (waves 0-3) =====
    if (wave < 4) {
      const int n0 = wave * 16;
      const u16* bp = A.o2wT + (size_t)(n0 + l15) * 608 + koff;
      f32x4 acc{};
#pragma unroll 4
      for (int kk = 0; kk < 608; kk += 32)
        acc = MF(*reinterpret_cast<const short8*>(&hl[l15][koff + kk]),
                 *reinterpret_cast<const short8*>(bp + kk), acc);
#pragma unroll
      for (int i = 0; i < 4; ++i)
        sl[crow + i][n0 + l15] = acc[i] + A.obs2b[n0 + l15];
    }
    __syncthreads();

    // ===== Phase 5: head outputs + stoch + xa =====
    {
      int r = tid >> 5, j = tid & 31;
      size_t orow = (size_t)(R0 + r) * 64 + t;
      float mean = sl[r][j];
      float sd = 2.f * sigf(0.5f * sl[r][32 + j]) + 0.1f;
      float st = mean +
                 sd * __builtin_nontemporal_load((const float*)&A.npo[orow * 32 + j]);
      float* ob = A.out + orow * 1392;
      __builtin_nontemporal_store(mean, ob + j);
      __builtin_nontemporal_store(sd, ob + 32 + j);
      __builtin_nontemporal_store(st, ob + 64 + j);
      xa[r][j] = f2bf(st);
    }
    if (tid < 256) {
      int r = tid >> 4, a = tid & 15;
      float av = (t < 63)
          ? __builtin_nontemporal_load(
                (const float*)&A.action[((size_t)(R0 + r) * 64 + t + 1) * 16 + a])
          : 0.f;
      xa[r][32 + a] = f2bf(av);
      xa[r][48 + a] = 0;
    }
    __syncthreads();

    // ===== Phase 6: next x =====
    if (t < 63) img1();
    __syncthreads();
  }
}

// ---------------- launch ----------------
extern "C" void kernel_launch(void* const* d_in, const int* in_sizes, int n_in,
                              void* d_out, int out_size, void* d_ws, size_t ws_size,
                              hipStream_t stream) {
  (void)in_sizes; (void)n_in; (void)out_size; (void)ws_size;
  const float* action = (const float*)d_in[0];
  const float* embed = (const float*)d_in[1];
  const float* npr = (const float*)d_in[2];
  const float* npo = (const float*)d_in[3];
  const float* img1w = (const float*)d_in[4];
  const float* img1b = (const float*)d_in[5];
  const float* gruw = (const float*)d_in[6];
  const float* grub = (const float*)d_in[7];
  const float* lns = (const float*)d_in[8];
  const float* lnb = (const float*)d_in[9];
  const float* img2w = (const float*)d_in[10];
  const float* img2b = (const float*)d_in[11];
  const float* img3w = (const float*)d_in[12];
  const float* img3b = (const float*)d_in[13];
  const float* obs1w = (const float*)d_in[14];
  const float* obs1b = (const float*)d_in[15];
  const float* obs2w = (const float*)d_in[16];
  const float* obs2b = (const float*)d_in[17];
  float* out = (float*)d_out;
  char* ws = (char*)d_ws;

  size_t off = 0;
  auto alloc = [&](size_t bytes) {
    size_t o = off;
    off += (bytes + 255) & ~(size_t)255;
    return o;
  };
  size_t o_embed = alloc(12288ull * 1024 * 2);  // reused as dall (12288x640)
  size_t o_epre = alloc(12288ull * 600 * 2);    // reused (with o_wemb) as h_img
  size_t o_wemb = alloc(1024ull * 600 * 2);
  size_t o_gruwT = alloc(1808ull * 1216 * 2);
  size_t o_o1wT = alloc(608ull * 608 * 2);
  size_t o_o2wT = alloc(64ull * 608 * 2);
  size_t o_w1pT = alloc(640ull * 64 * 2);
  size_t o_i2w = alloc(640ull * 600 * 2);
  size_t o_i3w = alloc(640ull * 64 * 2);

  u16* embed_bf = (u16*)(ws + o_embed);
  u16* dall = (u16*)(ws + o_embed);
  u16* epre = (u16*)(ws + o_epre);
  u16* himg = (u16*)(ws + o_epre);
  u16* wemb = (u16*)(ws + o_wemb);
  u16* gruwT = (u16*)(ws + o_gruwT);
  u16* o1wT = (u16*)(ws + o_o1wT);
  u16* o2wT = (u16*)(ws + o_o2wT);
  u16* w1pT = (u16*)(ws + o_w1pT);
  u16* i2wb = (u16*)(ws + o_i2w);
  u16* i3wb = (u16*)(ws + o_i3w);

  auto cgr = [](size_t total) {
    size_t g = (total + 255) / 256;
    return (unsigned)(g > 4096 ? 4096 : g);
  };

  // setup conversions
  conv_pad<<<cgr(12288ull * 1024), 256, 0, stream>>>(embed, embed_bf, 12288, 1024, 12288, 0);
  conv_pad<<<cgr(1024ull * 600), 256, 0, stream>>>(obs1w, wemb, 1024, 600, 1024, 600);
  conv_pad<<<cgr(640ull * 600), 256, 0, stream>>>(img2w, i2wb, 600, 600, 640, 0);
  conv_pad<<<cgr(640ull * 64), 256, 0, stream>>>(img3w, i3wb, 600, 64, 640, 0);
  conv_gruT<<<cgr(1808ull * 1216), 256, 0, stream>>>(gruw, gruwT);
  conv_T<<<cgr(608ull * 608), 256, 0, stream>>>(obs1w, o1wT, 600, 600, 608, 608);
  conv_T<<<cgr(64ull * 608), 256, 0, stream>>>(obs2w, o2wT, 600, 64, 608, 64);
  conv_T<<<cgr(640ull * 64), 256, 0, stream>>>(img1w, w1pT, 48, 600, 64, 640);

  // epre[t][b][600] = embed @ obs1_w[600:,:] + obs1_b   (bf16, t-major)
  gemm64<4><<<dim3(10, 192), 256, 0, stream>>>(embed_bf, 1024, wemb, 600, obs1b,
                                               epre, 600, 600, 600, 1024);

  // the scan: 12 fully independent blocks, zero inter-block communication
  ScanArgs sa;
  sa.gruwT = gruwT; sa.grub = grub; sa.lns = lns; sa.lnb = lnb;
  sa.dall = dall; sa.out = out;
  sa.o1wT = o1wT; sa.epre = epre;
  sa.o2wT = o2wT; sa.obs2b = obs2b; sa.npo = npo;
  sa.w1pT = w1pT; sa.img1b = img1b; sa.action = action;
  scan64<<<12, 512, 0, stream>>>(sa);

  // batched prior: h_img = elu(deter_all @ img2_w + img2_b), then img3 head
  gemm64<2><<<dim3(10, 192), 256, 0, stream>>>(dall, 640, i2wb, 600, img2b,
                                               himg, 640, 640, 600, 640);
  head_prior<<<192, 256, 0, stream>>>(himg, i3wb, img3b, npr, out);
}

// Round 11
// 5634.874 us; speedup vs baseline: 1.8482x; 1.8482x over previous
//
#include <hip/hip_runtime.h>

typedef unsigned short u16;
typedef __attribute__((ext_vector_type(8))) short short8;
typedef __attribute__((ext_vector_type(4))) float f32x4;

#define DEV __device__ __forceinline__

// B=192, T=64, ACT=16, EMB=1024, STOCH=32, DETER=600, HID=600
// out row stride 1392: [mean_po 0, std_po 32, stoch_po 64, deter 96,
//                       mean_pr 696, std_pr 728, stoch_pr 760, deter 792]
// xd row layout [192][1280]: [x 0..599 | 0 600..639 | deter 640..1239 | 0 ..1279]
#define XDS 1280
#define NSCAN 24

DEV u16 f2bf(float f) {
  unsigned u = __float_as_uint(f);
  u = (u + 0x7FFFu + ((u >> 16) & 1u)) >> 16;
  return (u16)u;
}
DEV float bf2f(u16 h) { return __uint_as_float(((unsigned)h) << 16); }
DEV float sigf(float x) { return 1.f / (1.f + __expf(-x)); }
DEV float eluf(float x) { return x > 0.f ? x : __expf(x) - 1.f; }
DEV f32x4 MF(short8 a, short8 b, f32x4 c) {
  return __builtin_amdgcn_mfma_f32_16x16x32_bf16(a, b, c, 0, 0, 0);
}

// ---- agent-coherent (sc1, MALL-served) helpers ----
DEV unsigned long long ald64(const void* p) {
  return __hip_atomic_load((const unsigned long long*)p, __ATOMIC_RELAXED,
                           __HIP_MEMORY_SCOPE_AGENT);
}
DEV short8 ald16B(const u16* p) {
  union { unsigned long long u[2]; short8 v; } x;
  x.u[0] = ald64(p);
  x.u[1] = ald64(p + 4);
  return x.v;
}
DEV void ast32(void* p, unsigned v) {
  __hip_atomic_store((unsigned*)p, v, __ATOMIC_RELAXED, __HIP_MEMORY_SCOPE_AGENT);
}
DEV unsigned ald32(const unsigned* p) {
  return __hip_atomic_load(p, __ATOMIC_RELAXED, __HIP_MEMORY_SCOPE_AGENT);
}

// ---------------- f32 -> bf16 with zero row padding (k-major) ----------------
__global__ __launch_bounds__(256) void conv_pad(const float* __restrict__ src,
                                                u16* __restrict__ dst,
                                                int K, int N, int Kpad, int srcRowOff) {
  size_t total = (size_t)Kpad * N;
  for (size_t idx = (size_t)blockIdx.x * 256 + threadIdx.x; idx < total;
       idx += (size_t)gridDim.x * 256) {
    int k = (int)(idx / (size_t)N);
    int n = (int)(idx % (size_t)N);
    dst[idx] = (k < K) ? f2bf(src[(size_t)(k + srcRowOff) * N + n]) : (u16)0;
  }
}

// ---------------- f32 [K0][N0] -> bf16 transposed [Npad][Kpad] ----------------
__global__ __launch_bounds__(256) void conv_T(const float* __restrict__ src,
                                              u16* __restrict__ dst,
                                              int K0, int N0, int Kpad, int Npad) {
  size_t total = (size_t)Npad * Kpad;
  for (size_t idx = (size_t)blockIdx.x * 256 + threadIdx.x; idx < total;
       idx += (size_t)gridDim.x * 256) {
    int n = (int)(idx / (size_t)Kpad);
    int k = (int)(idx % (size_t)Kpad);
    dst[idx] = (k < K0 && n < N0) ? f2bf(src[(size_t)k * N0 + n]) : (u16)0;
  }
}

// gruw [1200][1800] -> bf16 [1808 n][1280 k2]; k2<600 -> x-row k2,
// 640<=k2<1240 -> deter-row k2-40, else zero; n>=1800 zero.
__global__ __launch_bounds__(256) void conv_gruT(const float* __restrict__ src,
                                                 u16* __restrict__ dst) {
  size_t total = 1808ull * 1280;
  for (size_t idx = (size_t)blockIdx.x * 256 + threadIdx.x; idx < total;
       idx += (size_t)gridDim.x * 256) {
    int n = (int)(idx / 1280);
    int k2 = (int)(idx % 1280);
    int ko = (k2 < 600) ? k2 : (k2 >= 640 && k2 < 1240) ? (k2 - 40) : -1;
    dst[idx] = (n < 1800 && ko >= 0) ? f2bf(src[(size_t)ko * 1800 + n]) : (u16)0;
  }
}

// ---------------- MFMA 64x64 tile core (setup/tail GEMMs) ----
DEV void mfma_tile(const u16 (*As)[72], const u16 (*Bs)[72], int wm, int wn,
                   int lane, f32x4 acc[2][2]) {
#pragma unroll
  for (int s = 0; s < 2; ++s) {
    const int ko = s * 32 + ((lane >> 4) << 3);
    short8 a0 = *reinterpret_cast<const short8*>(&As[wm + (lane & 15)][ko]);
    short8 a1 = *reinterpret_cast<const short8*>(&As[wm + 16 + (lane & 15)][ko]);
    short8 b0 = *reinterpret_cast<const short8*>(&Bs[wn + (lane & 15)][ko]);
    short8 b1 = *reinterpret_cast<const short8*>(&Bs[wn + 16 + (lane & 15)][ko]);
    acc[0][0] = MF(a0, b0, acc[0][0]);
    acc[0][1] = MF(a0, b1, acc[0][1]);
    acc[1][0] = MF(a1, b0, acc[1][0]);
    acc[1][1] = MF(a1, b1, acc[1][1]);
  }
}

// ---------------- generic 64x64-tiled bf16 GEMM (setup/tail) ----------------
// EPI: 2 = +bias, elu, bf16 out ; 4 = +bias, bf16 out, epre-permuted store
template <int EPI>
__global__ __launch_bounds__(256) void gemm64(
    const u16* __restrict__ A, int lda, const u16* __restrict__ W, int ldw,
    const float* __restrict__ bias, void* __restrict__ Cv, int ldc,
    int Nstore, int N, int K) {
  __shared__ u16 As[64][72];
  __shared__ u16 Bs[64][72];
  const int tid = threadIdx.x, lane = tid & 63, wave = tid >> 6;
  const int wm = (wave & 1) * 32, wn = (wave >> 1) * 32;
  const int bn0 = blockIdx.x * 64, bm0 = blockIdx.y * 64;
  const int am = tid >> 2, ak0 = (tid & 3) * 16;
  const int bk = tid >> 3, bn = (tid & 7) * 8;

  f32x4 acc[2][2] = {};
  for (int k0 = 0; k0 < K; k0 += 64) {
    __syncthreads();
    {
      const u16* src = A + (size_t)(bm0 + am) * lda + k0 + ak0;
      *reinterpret_cast<short8*>(&As[am][ak0]) = *reinterpret_cast<const short8*>(src);
      *reinterpret_cast<short8*>(&As[am][ak0 + 8]) = *reinterpret_cast<const short8*>(src + 8);
    }
    {
      int gn = bn0 + bn;
#pragma unroll
      for (int h = 0; h < 2; ++h) {
        int kk = k0 + bk + h * 32;
        short8 v;
        if (gn + 7 < N) {
          v = *reinterpret_cast<const short8*>(W + (size_t)kk * ldw + gn);
        } else {
          for (int j = 0; j < 8; ++j)
            v[j] = (gn + j < N) ? (short)W[(size_t)kk * ldw + gn + j] : (short)0;
        }
#pragma unroll
        for (int j = 0; j < 8; ++j) Bs[bn + j][bk + h * 32] = (u16)v[j];
      }
    }
    __syncthreads();
    mfma_tile(As, Bs, wm, wn, lane, acc);
  }

#pragma unroll
  for (int r = 0; r < 2; ++r)
#pragma unroll
    for (int c = 0; c < 2; ++c)
#pragma unroll
      for (int i = 0; i < 4; ++i) {
        int grow = bm0 + wm + r * 16 + ((lane >> 4) << 2) + i;
        int gcol = bn0 + wn + c * 16 + (lane & 15);
        if (gcol >= Nstore) continue;
        bool ok = gcol < N;
        float v = acc[r][c][i] + (ok ? bias[gcol] : 0.f);
        if (EPI == 2) {
          v = eluf(v);
          ((u16*)Cv)[(size_t)grow * ldc + gcol] = ok ? f2bf(v) : (u16)0;
        } else {  // EPI 4: epre[t][b][600] layout
          size_t row2 = (size_t)(grow & 63) * 192 + (size_t)(grow >> 6);
          ((u16*)Cv)[row2 * 600 + gcol] = f2bf(v);
        }
      }
}

// ------- init: x(t=0)=elu(action part), deter=0, pads=0, flags=0 ----------
__global__ __launch_bounds__(256) void k_init(const float* __restrict__ action,
                                              const float* __restrict__ img1w,
                                              const float* __restrict__ img1b,
                                              u16* __restrict__ xd,
                                              unsigned* __restrict__ flags) {
  __shared__ float act[16];
  int b = blockIdx.x, tid = threadIdx.x;
  if (b == 0)
    for (int i = tid; i < 96 * 16; i += 256) flags[i] = 0;
  if (tid < 16) act[tid] = action[(size_t)b * 64 * 16 + tid];  // t = 0
  __syncthreads();
  for (int h = tid; h < 600; h += 256) {
    float s = img1b[h];
#pragma unroll
    for (int a = 0; a < 16; ++a) s += act[a] * img1w[(size_t)(32 + a) * 600 + h];
    xd[(size_t)b * XDS + h] = f2bf(eluf(s));
  }
  for (int j = tid; j < 680; j += 256) xd[(size_t)b * XDS + 600 + j] = 0;
}

// ---------------- batched prior head (tail; N=64 GEMM + dist outputs) --------
__global__ __launch_bounds__(256) void head_prior(
    const u16* __restrict__ A, const u16* __restrict__ W,
    const float* __restrict__ bias64, const float* __restrict__ noise,
    float* __restrict__ out) {
  __shared__ u16 As[64][72];
  __shared__ u16 Bs[64][72];
  __shared__ float sl[64][68];
  const int tid = threadIdx.x, lane = tid & 63, wave = tid >> 6;
  const int wm = (wave & 1) * 32, wn = (wave >> 1) * 32;
  const int bm0 = blockIdx.x * 64;
  const int am = tid >> 2, ak0 = (tid & 3) * 16;
  const int bk = tid >> 3, bn = (tid & 7) * 8;

  f32x4 acc[2][2] = {};
  for (int k0 = 0; k0 < 640; k0 += 64) {
    __syncthreads();
    {
      const u16* src = A + (size_t)(bm0 + am) * 640 + k0 + ak0;
      *reinterpret_cast<short8*>(&As[am][ak0]) = *reinterpret_cast<const short8*>(src);
      *reinterpret_cast<short8*>(&As[am][ak0 + 8]) = *reinterpret_cast<const short8*>(src + 8);
    }
#pragma unroll
    for (int h = 0; h < 2; ++h) {
      int kk = k0 + bk + h * 32;
      short8 v = *reinterpret_cast<const short8*>(W + (size_t)kk * 64 + bn);
#pragma unroll
      for (int j = 0; j < 8; ++j) Bs[bn + j][bk + h * 32] = (u16)v[j];
    }
    __syncthreads();
    mfma_tile(As, Bs, wm, wn, lane, acc);
  }
#pragma unroll
  for (int r = 0; r < 2; ++r)
#pragma unroll
    for (int c = 0; c < 2; ++c)
#pragma unroll
      for (int i = 0; i < 4; ++i) {
        int col = wn + c * 16 + (lane & 15);
        sl[wm + r * 16 + ((lane >> 4) << 2) + i][col] = acc[r][c][i] + bias64[col];
      }
  __syncthreads();
  for (int task = tid; task < 64 * 32; task += 256) {
    int r = task >> 5, j = task & 31;
    size_t orow = (size_t)(bm0 + r);
    size_t base = orow * 1392 + 696;
    float mean = sl[r][j];
    float sd = 2.f * sigf(0.5f * sl[r][32 + j]) + 0.1f;
    float st = mean + sd * noise[orow * 32 + j];
    out[base + j] = mean;
    out[base + 32 + j] = sd;
    out[base + 64 + j] = st;
  }
}

// ---- unified scan: 24 blocks; each owns 8 batch rows (carry/LN/obs) AND an
// ---- exclusive ~80-col slice of the GRU output (N-split over all 192 rows).
// ---- 2 handoffs/step: xd all-gather (sc1), parts exchange (sc1 bf16).
// ---- flags (64B stride): partsF @ [0+b]*16, deterF @ [32+b]*16, xF @ [64+b]*16
struct ScanArgs {
  u16* xd;            // [192][1280] carry (sc1)
  u16* parts;         // [192][1808] bf16 (sc1)
  const u16* gruwT;   // [1808 n][1280 k] remapped (cached)
  const float* grub;
  const float* lns;
  const float* lnb;
  u16* dall;          // [12288][640] (nt; read by tail)
  float* out;
  const u16* o1wT;    // [608][608]
  const u16* epre;    // [64][192][600] (t-major, nt loads)
  const u16* o2wT;    // [64][608]
  const float* obs2b;
  const float* npo;
  const u16* w1pT;    // [640][64]
  const float* img1b;
  const float* action;
  unsigned* flags;
};

__global__ __launch_bounds__(512, 1) void scan64(ScanArgs A) {
  const int bid = blockIdx.x, tid = threadIdx.x;
  const int lane = tid & 63, wave = tid >> 6;
  const int l15 = lane & 15;
  const int koff = (lane >> 4) << 3;
  const int crow = (lane >> 4) << 2;
  const int R0 = bid * 8;
  const int gStart = bid * 4 + (bid < 17 ? bid : 17);
  const int gCount = (bid < 17) ? 5 : 4;
  const int nB8 = gCount * 16 * 8;

  __shared__ float dsh[8][600];                 // persistent deter carry (f32)
  __shared__ __align__(16) char Rm[117504];     // phase-overlaid region
  u16 (*Ab)[192][72] = (u16(*)[192][72])Rm;                 // 3 bufs, 82944 B
  u16 (*Bb)[80][72] = (u16(*)[80][72])(Rm + 82944);         // 3 bufs, 34560 B
  u16 (*pl)[1808] = (u16(*)[1808])Rm;                       // post-GEMM overlay
  u16 (*dl)[616] = (u16(*)[616])(Rm + 28928);
  u16 (*hl)[616] = (u16(*)[616])(Rm + 48640);
  u16* es = (u16*)(Rm + 68352);                             // [8][608]
  u16 (*xa)[72] = (u16(*)[72])(Rm + 78080);
  float (*sl)[68] = (float(*)[68])(Rm + 80384);
  unsigned* F = A.flags;

  for (int i = tid; i < 8 * 600; i += 512) ((float*)dsh)[i] = 0.f;

  for (int t = 0; t < 64; ++t) {
    f32x4 acc[5][2] = {};
    // ================= GRU GEMM: all 192 rows x my col-slice =================
    for (int kh = 0; kh < 2; ++kh) {
      {  // wait deter(t-1) (kh=0) / x(t) (kh=1)
        const unsigned tgt = (unsigned)t;
        const int base = kh ? 64 : 32;
        __syncthreads();
        if (tid < 64) {
          for (;;) {
            unsigned v = (lane < NSCAN) ? ald32(&F[(base + lane) * 16]) : tgt;
            if (__all((int)(v >= tgt))) break;
            __builtin_amdgcn_s_sleep(2);
          }
        }
        __syncthreads();
      }
      const int kb = kh * 640;
      // prologue: stage tiles 0,1 into ring bufs 0,1
#pragma unroll
      for (int pre = 0; pre < 2; ++pre) {
        for (int idx = tid; idx < 1536; idx += 512) {
          int r = idx >> 3, o = (idx & 7) * 8;
          *reinterpret_cast<short8*>(&Ab[pre][r][o]) =
              ald16B(A.xd + (size_t)r * XDS + kb + pre * 64 + o);
        }
        for (int idx = tid; idx < nB8; idx += 512) {
          int r = idx >> 3, o = (idx & 7) * 8;
          *reinterpret_cast<short8*>(&Bb[pre][r][o]) =
              *reinterpret_cast<const short8*>(
                  A.gruwT + (size_t)(16 * gStart + r) * 1280 + kb + pre * 64 + o);
        }
      }
      for (int kt = 0; kt < 10; ++kt) {
        __syncthreads();
        if (kt < 8) {
          const int nb = (kt + 2) % 3;
          const int ko2 = kb + (kt + 2) * 64;
          for (int idx = tid; idx < 1536; idx += 512) {
            int r = idx >> 3, o = (idx & 7) * 8;
            *reinterpret_cast<short8*>(&Ab[nb][r][o]) =
                ald16B(A.xd + (size_t)r * XDS + ko2 + o);
          }
          for (int idx = tid; idx < nB8; idx += 512) {
            int r = idx >> 3, o = (idx & 7) * 8;
            *reinterpret_cast<short8*>(&Bb[nb][r][o]) =
                *reinterpret_cast<const short8*>(
                    A.gruwT + (size_t)(16 * gStart + r) * 1280 + ko2 + o);
          }
        }
        if (wave < 6) {
          const int cb = kt % 3;
#pragma unroll
          for (int ks = 0; ks < 2; ++ks) {
            short8 a0 = *reinterpret_cast<const short8*>(
                &Ab[cb][32 * wave + l15][ks * 32 + koff]);
            short8 a1 = *reinterpret_cast<const short8*>(
                &Ab[cb][32 * wave + 16 + l15][ks * 32 + koff]);
#pragma unroll
            for (int q = 0; q < 5; ++q) {
              if (q < gCount) {
                short8 b = *reinterpret_cast<const short8*>(
                    &Bb[cb][16 * q + l15][ks * 32 + koff]);
                acc[q][0] = MF(a0, b, acc[q][0]);
                acc[q][1] = MF(a1, b, acc[q][1]);
              }
            }
          }
        }
      }
      __syncthreads();
    }
    // store parts slice (bf16, sc1)
    if (wave < 6) {
#pragma unroll
      for (int q = 0; q < 5; ++q) {
        if (q < gCount) {
          int c = 16 * (gStart + q) + l15;
#pragma unroll
          for (int ms = 0; ms < 2; ++ms)
#pragma unroll
            for (int i = 0; i < 4; ++i) {
              int row = 32 * wave + 16 * ms + crow + i;
              unsigned hv = f2bf(acc[q][ms][i]);
              unsigned ov = (unsigned)__shfl_xor((int)hv, 1);
              if (!(lane & 1) && c < 1800)
                ast32(A.parts + (size_t)row * 1808 + c, hv | (ov << 16));
            }
        }
      }
    }
    __syncthreads();
    if (tid == 0) ast32(&F[(0 + bid) * 16], (unsigned)(t + 1));

    // zero dl/hl/xa (R-region was clobbered by GEMM bufs)
    for (int i = tid; i < 16 * 308; i += 512) ((unsigned*)dl)[i] = 0;
    for (int i = tid; i < 16 * 308; i += 512) ((unsigned*)hl)[i] = 0;
    for (int i = tid; i < 16 * 36; i += 512) ((unsigned*)xa)[i] = 0;

    {  // wait all parts
      const unsigned tgt = (unsigned)(t + 1);
      __syncthreads();
      if (tid < 64) {
        for (;;) {
          unsigned v = (lane < NSCAN) ? ald32(&F[(0 + lane) * 16]) : tgt;
          if (__all((int)(v >= tgt))) break;
          __builtin_amdgcn_s_sleep(2);
        }
      }
      __syncthreads();
    }
    // read own 8 rows of parts (wave = row)
    {
      const u16* pr = A.parts + (size_t)(R0 + wave) * 1808;
#pragma unroll
      for (int it = 0; it < 8; ++it) {
        int p = (it * 64 + lane) * 4;
        if (p < 1800)
          *reinterpret_cast<unsigned long long*>(&pl[wave][p]) = ald64(pr + p);
      }
    }
    __syncthreads();
    // LN + gates + deter update (wave = row)
    {
      const int rr = wave;
      float s = 0.f;
      for (int j = lane; j < 1800; j += 64) s += bf2f(pl[rr][j]) + A.grub[j];
#pragma unroll
      for (int o = 32; o; o >>= 1) s += __shfl_xor(s, o);
      float m = s * (1.f / 1800.f);
      float q2 = 0.f;
      for (int j = lane; j < 1800; j += 64) {
        float d = bf2f(pl[rr][j]) + A.grub[j] - m;
        q2 += d * d;
      }
#pragma unroll
      for (int o = 32; o; o >>= 1) q2 += __shfl_xor(q2, o);
      float rstd = rsqrtf(q2 * (1.f / 1800.f) + 1e-5f);
      size_t orow = (size_t)(R0 + rr) * 64 + t;
      for (int j = lane; j < 600; j += 64) {
        float p0 = (bf2f(pl[rr][j]) + A.grub[j] - m) * rstd * A.lns[j] + A.lnb[j];
        float p1 = (bf2f(pl[rr][600 + j]) + A.grub[600 + j] - m) * rstd * A.lns[600 + j] +
                   A.lnb[600 + j];
        float p2 = (bf2f(pl[rr][1200 + j]) + A.grub[1200 + j] - m) * rstd *
                       A.lns[1200 + j] + A.lnb[1200 + j];
        float r = sigf(p0);
        float cd = tanhf(r * p1);
        float u = sigf(p2 - 1.f);
        float dn = u * cd + (1.f - u) * dsh[rr][j];
        dsh[rr][j] = dn;
        dl[rr][j] = f2bf(dn);
        float* ob = A.out + orow * 1392;
        __builtin_nontemporal_store(dn, ob + 96 + j);
        __builtin_nontemporal_store(dn, ob + 792 + j);
        unsigned hv = f2bf(dn);
        unsigned ov = (unsigned)__shfl_xor((int)hv, 1);
        if (!(lane & 1)) {
          ast32(A.xd + (size_t)(R0 + rr) * XDS + 640 + j, hv | (ov << 16));
          __builtin_nontemporal_store(hv | (ov << 16),
                                      (unsigned*)(A.dall + orow * 640 + j));
        }
      }
      if (lane < 20)
        __builtin_nontemporal_store(0u,
                                    (unsigned*)(A.dall + orow * 640 + 600 + 2 * lane));
    }
    __syncthreads();
    if (tid == 0) ast32(&F[(32 + bid) * 16], (unsigned)(t + 1));

    // epre stage (local)
    for (int idx = tid; idx < 600; idx += 512) {
      int r = idx / 75, ko2 = (idx - r * 75) * 8;
      short8 ev = __builtin_nontemporal_load(
          (const short8*)(A.epre + ((size_t)t * 192 + R0 + r) * 600 + ko2));
      *reinterpret_cast<short8*>(&es[r * 608 + ko2]) = ev;
    }
    __syncthreads();
    // obs1: hl = elu(deter @ obs1_w + epre)
#pragma unroll
    for (int q = 0; q < 5; ++q) {
      int g = wave + 8 * q;
      if (g < 38) {
        const u16* bp = A.o1wT + (size_t)(16 * g + l15) * 608 + koff;
        f32x4 ac{};
        for (int kk = 0; kk < 608; kk += 32)
          ac = MF(*reinterpret_cast<const short8*>(&dl[l15][koff + kk]),
                  *reinterpret_cast<const short8*>(bp + kk), ac);
        int cw = 16 * g + l15;
        if (cw < 600) {
#pragma unroll
          for (int i = 0; i < 4; ++i) {
            int r = crow + i;
            if (r < 8) hl[r][cw] = f2bf(eluf(ac[i] + bf2f(es[r * 608 + cw])));
          }
        }
      }
    }
    __syncthreads();
    // obs2 (waves 0-3)
    if (wave < 4) {
      const int n0 = wave * 16;
      const u16* bp = A.o2wT + (size_t)(n0 + l15) * 608 + koff;
      f32x4 ac{};
      for (int kk = 0; kk < 608; kk += 32)
        ac = MF(*reinterpret_cast<const short8*>(&hl[l15][koff + kk]),
                *reinterpret_cast<const short8*>(bp + kk), ac);
#pragma unroll
      for (int i = 0; i < 4; ++i)
        sl[crow + i][n0 + l15] = ac[i] + A.obs2b[n0 + l15];
    }
    __syncthreads();
    // head outputs + stoch + xa
    if (tid < 256) {
      int r = tid >> 5, j = tid & 31;
      size_t orow = (size_t)(R0 + r) * 64 + t;
      float mean = sl[r][j];
      float sd = 2.f * sigf(0.5f * sl[r][32 + j]) + 0.1f;
      float st = mean +
                 sd * __builtin_nontemporal_load((const float*)&A.npo[orow * 32 + j]);
      float* ob = A.out + orow * 1392;
      __builtin_nontemporal_store(mean, ob + j);
      __builtin_nontemporal_store(sd, ob + 32 + j);
      __builtin_nontemporal_store(st, ob + 64 + j);
      xa[r][j] = f2bf(st);
    } else if (tid < 384) {
      int r = (tid - 256) >> 4, a2 = tid & 15;
      float av = (t < 63)
                     ? __builtin_nontemporal_load(
                           (const float*)&A.action[((size_t)(R0 + r) * 64 + t + 1) * 16 + a2])
                     : 0.f;
      xa[r][32 + a2] = f2bf(av);
    }
    __syncthreads();
    // img1 -> x(t+1) -> xd (sc1)
    if (t < 63) {
#pragma unroll
      for (int q = 0; q < 5; ++q) {
        int g = wave + 8 * q;
        if (g < 38) {
          const u16* bp = A.w1pT + (size_t)(16 * g + l15) * 64 + koff;
          f32x4 ax{};
          ax = MF(*reinterpret_cast<const short8*>(&xa[l15][koff]),
                  *reinterpret_cast<const short8*>(bp), ax);
          ax = MF(*reinterpret_cast<const short8*>(&xa[l15][32 + koff]),
                  *reinterpret_cast<const short8*>(bp + 32), ax);
          int cx = 16 * g + l15;
          if (cx < 600) {
            float bi = A.img1b[cx];
#pragma unroll
            for (int i = 0; i < 4; ++i) {
              int r = crow + i;
              unsigned hv = f2bf(eluf(ax[i] + bi));
              unsigned ov = (unsigned)__shfl_xor((int)hv, 1);
              if (!(lane & 1) && r < 8)
                ast32(A.xd + (size_t)(R0 + r) * XDS + cx, hv | (ov << 16));
            }
          }
        }
      }
    }
    __syncthreads();
    if (tid == 0) ast32(&F[(64 + bid) * 16], (unsigned)(t + 1));
  }
}

// ---------------- launch ----------------
extern "C" void kernel_launch(void* const* d_in, const int* in_sizes, int n_in,
                              void* d_out, int out_size, void* d_ws, size_t ws_size,
                              hipStream_t stream) {
  (void)in_sizes; (void)n_in; (void)out_size; (void)ws_size;
  const float* action = (const float*)d_in[0];
  const float* embed = (const float*)d_in[1];
  const float* npr = (const float*)d_in[2];
  const float* npo = (const float*)d_in[3];
  const float* img1w = (const float*)d_in[4];
  const float* img1b = (const float*)d_in[5];
  const float* gruw = (const float*)d_in[6];
  const float* grub = (const float*)d_in[7];
  const float* lns = (const float*)d_in[8];
  const float* lnb = (const float*)d_in[9];
  const float* img2w = (const float*)d_in[10];
  const float* img2b = (const float*)d_in[11];
  const float* img3w = (const float*)d_in[12];
  const float* img3b = (const float*)d_in[13];
  const float* obs1w = (const float*)d_in[14];
  const float* obs1b = (const float*)d_in[15];
  const float* obs2w = (const float*)d_in[16];
  const float* obs2b = (const float*)d_in[17];
  float* out = (float*)d_out;
  char* ws = (char*)d_ws;

  size_t off = 0;
  auto alloc = [&](size_t bytes) {
    size_t o = off;
    off += (bytes + 255) & ~(size_t)255;
    return o;
  };
  size_t o_bar = alloc(96 * 16 * 4);
  size_t o_embed = alloc(12288ull * 1024 * 2);  // reused as dall (12288x640)
  size_t o_epre = alloc(12288ull * 600 * 2);    // reused (with o_wemb) as h_img
  size_t o_wemb = alloc(1024ull * 600 * 2);
  size_t o_gruwT = alloc(1808ull * 1280 * 2);
  size_t o_o1wT = alloc(608ull * 608 * 2);
  size_t o_o2wT = alloc(64ull * 608 * 2);
  size_t o_w1pT = alloc(640ull * 64 * 2);
  size_t o_i2w = alloc(640ull * 600 * 2);
  size_t o_i3w = alloc(640ull * 64 * 2);
  size_t o_xd = alloc(192ull * XDS * 2);
  size_t o_parts = alloc(192ull * 1808 * 2);

  unsigned* flags = (unsigned*)(ws + o_bar);
  u16* embed_bf = (u16*)(ws + o_embed);
  u16* dall = (u16*)(ws + o_embed);
  u16* epre = (u16*)(ws + o_epre);
  u16* himg = (u16*)(ws + o_epre);
  u16* wemb = (u16*)(ws + o_wemb);
  u16* gruwT = (u16*)(ws + o_gruwT);
  u16* o1wT = (u16*)(ws + o_o1wT);
  u16* o2wT = (u16*)(ws + o_o2wT);
  u16* w1pT = (u16*)(ws + o_w1pT);
  u16* i2wb = (u16*)(ws + o_i2w);
  u16* i3wb = (u16*)(ws + o_i3w);
  u16* xd = (u16*)(ws + o_xd);
  u16* parts = (u16*)(ws + o_parts);

  auto cgr = [](size_t total) {
    size_t g = (total + 255) / 256;
    return (unsigned)(g > 4096 ? 4096 : g);
  };

  // setup conversions
  conv_pad<<<cgr(12288ull * 1024), 256, 0, stream>>>(embed, embed_bf, 12288, 1024, 12288, 0);
  conv_pad<<<cgr(1024ull * 600), 256, 0, stream>>>(obs1w, wemb, 1024, 600, 1024, 600);
  conv_pad<<<cgr(640ull * 600), 256, 0, stream>>>(img2w, i2wb, 600, 600, 640, 0);
  conv_pad<<<cgr(640ull * 64), 256, 0, stream>>>(img3w, i3wb, 600, 64, 640, 0);
  conv_gruT<<<cgr(1808ull * 1280), 256, 0, stream>>>(gruw, gruwT);
  conv_T<<<cgr(608ull * 608), 256, 0, stream>>>(obs1w, o1wT, 600, 600, 608, 608);
  conv_T<<<cgr(64ull * 608), 256, 0, stream>>>(obs2w, o2wT, 600, 64, 608, 64);
  conv_T<<<cgr(640ull * 64), 256, 0, stream>>>(img1w, w1pT, 48, 600, 64, 640);

  k_init<<<192, 256, 0, stream>>>(action, img1w, img1b, xd, flags);

  // epre[t][b][600] = embed @ obs1_w[600:,:] + obs1_b   (bf16, t-major)
  gemm64<4><<<dim3(10, 192), 256, 0, stream>>>(embed_bf, 1024, wemb, 600, obs1b,
                                               epre, 600, 600, 600, 1024);

  // unified scan: 24 blocks, 2 handoffs/step
  ScanArgs sa;
  sa.xd = xd; sa.parts = parts;
  sa.gruwT = gruwT; sa.grub = grub; sa.lns = lns; sa.lnb = lnb;
  sa.dall = dall; sa.out = out;
  sa.o1wT = o1wT; sa.epre = epre;
  sa.o2wT = o2wT; sa.obs2b = obs2b; sa.npo = npo;
  sa.w1pT = w1pT; sa.img1b = img1b; sa.action = action;
  sa.flags = flags;
  scan64<<<NSCAN, 512, 0, stream>>>(sa);

  // batched prior: h_img = elu(deter_all @ img2_w + img2_b), then img3 head
  gemm64<2><<<dim3(10, 192), 256, 0, stream>>>(dall, 640, i2wb, 600, img2b,
                                               himg, 640, 640, 600, 640);
  head_prior<<<192, 256, 0, stream>>>(himg, i3wb, img3b, npr, out);
}